// Round 10
// baseline (909.274 us; speedup 1.0000x reference)
//
#include <hip/hip_runtime.h>

#define BATCH 4096
#define SEQ   2048
#define EMB   10
#define HID   50
#define VOCAB 14
#define TROW  2052     // token row stride bytes (u8): /4=513 ≡ 1 mod 32 -> conflict-free

using bf16x8 = __attribute__((ext_vector_type(8))) short;
using f32x4  = __attribute__((ext_vector_type(4))) float;

__device__ __forceinline__ short f2bf(float f) {
  unsigned u = __builtin_bit_cast(unsigned, f);
  u = (u + 0x7FFFu + ((u >> 16) & 1u)) >> 16;   // round-to-nearest-even
  return (short)u;
}
__device__ __forceinline__ unsigned f2bf2(float lo, float hi) {
  return (unsigned)(unsigned short)f2bf(lo) | ((unsigned)(unsigned short)f2bf(hi) << 16);
}
__device__ __forceinline__ float fsigm(float x) {
  return __builtin_amdgcn_rcpf(1.0f + __builtin_amdgcn_exp2f(x * -1.44269504f));
}

// ---------------------------------------------------------------------------
// Pack A fragments (bf16, pre-scaled) for mfma_f32_16x16x32_bf16.
// Tile map (q = row quad, g = row&3 gate, i/f/o rows x -log2e, g x -2log2e):
//   tiles 0..7  (fat pairs, wave {1,2,4,7} rank f, tile 2f+i): jh = 8f + 2q + i
//   tiles 8..11 (rot fixed, wave {0,3,5,6} rank r):            jh = 32 + 4r + q
//   tile  12    (rotating, owner = rank T&3):                  jh = 48 + q (q<2; rest pad)
//   k < 50 : W_hh[R][k]*scale ; k >= 50 : gxi[v=k-50][R]*scale,  R = g*50+jh
// ---------------------------------------------------------------------------
__global__ void prep_kernel(const float* __restrict__ emb,  const float* __restrict__ W_ih,
                            const float* __restrict__ W_hh, const float* __restrict__ b_ih,
                            const float* __restrict__ b_hh, short* __restrict__ Apack) {
  int idx = blockIdx.x * 256 + threadIdx.x;       // total 13*2*64*8 = 13312
  if (idx >= 13 * 2 * 64 * 8) return;
  int j    = idx & 7;
  int lane = (idx >> 3) & 63;
  int kf   = (idx >> 9) & 1;
  int tid  = idx >> 10;                            // tile 0..12
  int m    = lane & 15;
  int q    = m >> 2, g = m & 3;
  int jh;
  if (tid < 8)       { int f = tid >> 1, i = tid & 1; jh = 8 * f + 2 * q + i; }
  else if (tid < 12) { int r = tid - 8;               jh = 32 + 4 * r + q;    }
  else               { jh = (q < 2) ? (48 + q) : 999; }
  int k    = kf * 32 + (lane >> 4) * 8 + j;
  float v = 0.0f;
  if (jh < HID) {
    int R = g * HID + jh;
    float scale = (g == 2) ? -2.885390082f : -1.442695041f;
    if (k < HID) {
      v = W_hh[R * HID + k] * scale;
    } else {
      int vo = k - HID;                            // vocab id 0..13
      float s = b_ih[R] + b_hh[R];
      for (int e = 0; e < EMB; ++e) s += emb[vo * EMB + e] * W_ih[R * EMB + e];
      v = s * scale;
    }
  }
  Apack[idx] = f2bf(v);
}

// ---------------------------------------------------------------------------
// Main: 256 wgs x 512 threads (8 waves), one wg owns 16 batch rows.
// Fat waves {1,2,4,7}: 2 fixed tiles each (jh 0..31, adjacent pairs, packed
// b32 h-write, paired-rcp cells). Rotating waves {0,3,5,6}: 1 fixed tile
// (jh 32..47) + tile 12 (jh 48,49) every 4th step (owner = rank T&3), its
// c/h state in LDS (handoff crosses the step barrier). Every SIMD carries
// 3.25 tiles/step under both wave->SIMD mappings. One-hot duty: waves 0,5.
// Tokens staged once to LDS as u8; all loop LDS addresses loop-invariant.
// ---------------------------------------------------------------------------
__global__ __launch_bounds__(512, 1) void lstm_kernel(
    const int* __restrict__ tokens, const short* __restrict__ Apack,
    const float* __restrict__ W1, const float* __restrict__ b1,
    const float* __restrict__ W2, const float* __restrict__ b2,
    float* __restrict__ out) {
  __shared__ __align__(16) unsigned char toku8[16 * TROW];   // 32832 B
  __shared__ __align__(16) short hbuf[2][16 * 64];           // 4096 B, swizzled
  __shared__ float cst12[32], hst12[32];                     // tile-12 state
  __shared__ float hfin[16 * 52];
  __shared__ float mlp_hid[16 * 52];

  const int tid  = threadIdx.x;
  const int lane = tid & 63;
  const int wv   = tid >> 6;
  const int b0   = blockIdx.x * 16;
  const int bB   = lane & 15;          // batch col (B-frag & C col)
  const int jj   = lane >> 4;          // quad

  const unsigned FATM = 0x96u, ROTM = 0x69u;     // {1,2,4,7} / {0,3,5,6}
  const bool fat = (FATM >> wv) & 1;
  const int  fr  = __builtin_popcount(FATM & ((1u << wv) - 1));
  const int  rr  = __builtin_popcount(ROTM & ((1u << wv) - 1));
  const int  p   = fr * 4 + jj;        // fat: jh pair (2p, 2p+1), 0..31
  const int  jhF = 32 + 4 * rr + jj;   // rot fixed jh, 32..47

  // persistent A fragments
  const int t0 = fat ? (2 * fr) : (8 + rr);
  bf16x8 Af00 = *(const bf16x8*)(Apack + ((t0 * 2 + 0) * 64 + lane) * 8);
  bf16x8 Af01 = *(const bf16x8*)(Apack + ((t0 * 2 + 1) * 64 + lane) * 8);
  bf16x8 Af10 = {}, Af11 = {};
  if (fat) {   // second fixed tile
    Af10 = *(const bf16x8*)(Apack + (((t0 + 1) * 2 + 0) * 64 + lane) * 8);
    Af11 = *(const bf16x8*)(Apack + (((t0 + 1) * 2 + 1) * 64 + lane) * 8);
  } else {     // tile 12 (rotating)
    Af10 = *(const bf16x8*)(Apack + ((12 * 2 + 0) * 64 + lane) * 8);
    Af11 = *(const bf16x8*)(Apack + ((12 * 2 + 1) * 64 + lane) * 8);
  }

  // one-hot duty: waves 0,5 -> 56 lanes each (8 batch rows x 7 words)
  const bool ohact = (wv == 0 || wv == 5) && (lane < 56);
  const int ohr   = ((wv == 5) ? 8 : 0) + lane / 7;
  const int ohsub = lane % 7;
  const int ohoct = (ohsub < 3) ? 6 : 7;
  const int ohinn = (ohsub < 3) ? (4 + 4 * ohsub) : (4 * (ohsub - 3));
  const int ohb   = ohr * 128 + 16 * ((ohoct + ohr) & 7) + ohinn;
  const int ohv0  = 2 * ohsub, ohv1 = 2 * ohsub + 1;

  // ---- stage tokens (int32 -> u8), zero hbuf[0] and tile-12 state
  for (int i = tid; i < 16 * 512; i += 512) {
    int row = i >> 9, c4 = i & 511;
    int4 tv = *(const int4*)&tokens[(b0 + row) * SEQ + 4 * c4];
    unsigned pk = (tv.x & 0xFF) | ((tv.y & 0xFF) << 8) |
                  ((tv.z & 0xFF) << 16) | ((tv.w & 0xFF) << 24);
    *(unsigned*)&toku8[row * TROW + 4 * c4] = pk;
  }
  for (int i = tid; i < 1024; i += 512) hbuf[0][i] = 0;
  if (tid < 32) { cst12[tid] = 0.f; hst12[tid] = 0.f; }
  __syncthreads();

  // loop-invariant LDS byte offsets (XOR-swizzled 128 B rows)
  char* hb = (char*)hbuf;
  const int rb0   = bB * 128 + 16 * ((jj + bB) & 7);          // B octet jj
  const int rb1   = bB * 128 + 16 * (((jj + 4) + bB) & 7);    // B octet jj+4
  const int hwb32 = bB * 128 + 16 * (((p >> 2) + bB) & 7) + ((4 * p) & 15);
  const int hwb16 = bB * 128 + 16 * (((jhF >> 3) + bB) & 7) + 2 * (jhF & 7);
  const int hw12  = bB * 128 + 16 * ((6 + bB) & 7) + 2 * jj;  // jh 48+jj (jj<2)
  const int ci    = jj * 16 + bB;                              // tile-12 state idx
  const unsigned char* myrow = &toku8[bB * TROW];
  const unsigned char* ohtok = &toku8[ohr * TROW];

  // one-hot for t=0
  if (ohact) {
    int tk = ohtok[0];
    unsigned wb = ((tk == ohv0) ? 0x3F80u : 0u) | ((tk == ohv1) ? 0x3F800000u : 0u);
    *(unsigned*)(hb + ohb) = wb;
  }

  float c0 = 0.f, h0 = 0.f, c1 = 0.f, h1 = 0.f;
  unsigned mp = 0;

  for (int t = 0; t < SEQ; t += 16) {
#pragma unroll
    for (int u = 0; u < 16; ++u) {
      const int T  = t + u;
      const int PB = (u & 1) * 2048, PN = PB ^ 2048;
      __syncthreads();   // hbuf[PB] + tile-12 state ready; lgkmcnt-only drain

      bf16x8 Bf0 = *(const bf16x8*)(hb + PB + rb0);
      bf16x8 Bf1 = *(const bf16x8*)(hb + PB + rb1);

      if (ohact && T + 1 < SEQ) {
        int tk = ohtok[T + 1];
        unsigned wb = ((tk == ohv0) ? 0x3F80u : 0u) |
                      ((tk == ohv1) ? 0x3F800000u : 0u);
        *(unsigned*)(hb + PN + ohb) = wb;
      }
      if ((u & 3) == 0) mp = *(const unsigned*)(myrow + T);   // tokens T..T+3

      f32x4 acc0 = {0.f, 0.f, 0.f, 0.f};
      acc0 = __builtin_amdgcn_mfma_f32_16x16x32_bf16(Af00, Bf0, acc0, 0, 0, 0);
      acc0 = __builtin_amdgcn_mfma_f32_16x16x32_bf16(Af01, Bf1, acc0, 0, 0, 0);

      const bool keep = (((mp >> (8 * (u & 3))) & 0xFF) != 0);

      // paired fused-fraction cells (10 exp2 + 2 rcp for 2 cells)
#define CELL2(ACCA, ACCB, CA, HA, CB, HB)                                      \
      {                                                                        \
        float eA0 = __builtin_amdgcn_exp2f(ACCA[0]);                           \
        float eB0 = __builtin_amdgcn_exp2f(ACCA[1]);                           \
        float eC0 = __builtin_amdgcn_exp2f(ACCA[2]);                           \
        float eG0 = __builtin_amdgcn_exp2f(ACCA[3]);                           \
        float eA1 = __builtin_amdgcn_exp2f(ACCB[0]);                           \
        float eB1 = __builtin_amdgcn_exp2f(ACCB[1]);                           \
        float eC1 = __builtin_amdgcn_exp2f(ACCB[2]);                           \
        float eG1 = __builtin_amdgcn_exp2f(ACCB[3]);                           \
        float a10 = 1.f + eA0, b10 = 1.f + eB0, c10 = 1.f + eC0, g10 = 1.f + eG0; \
        float a11 = 1.f + eA1, b11 = 1.f + eB1, c11 = 1.f + eC1, g11 = 1.f + eG1; \
        float P0 = a10 * c10, P1 = a11 * c11;                                  \
        float t10 = __builtin_fmaf(-eC0, b10, b10);                            \
        float t11 = __builtin_fmaf(-eC1, b11, b11);                            \
        float num0 = __builtin_fmaf(CA, P0, t10);                              \
        float num1 = __builtin_fmaf(CB, P1, t11);                              \
        float den0 = P0 * b10, den1 = P1 * b11;                                \
        float r  = __builtin_amdgcn_rcpf(den0 * den1);                         \
        float cn0 = num0 * (den1 * r);                                         \
        float cn1 = num1 * (den0 * r);                                         \
        float cl0 = fminf(cn0 * -2.885390082f, 40.0f);                         \
        float cl1 = fminf(cn1 * -2.885390082f, 40.0f);                         \
        float H0 = __builtin_amdgcn_exp2f(cl0);                                \
        float H1 = __builtin_amdgcn_exp2f(cl1);                                \
        float hd0 = g10 * (1.f + H0);                                          \
        float hd1 = g11 * (1.f + H1);                                          \
        float rh = __builtin_amdgcn_rcpf(hd0 * hd1);                           \
        float hn0 = (1.f - H0) * (hd1 * rh);                                   \
        float hn1 = (1.f - H1) * (hd0 * rh);                                   \
        CA = keep ? cn0 : CA;  HA = keep ? hn0 : HA;                           \
        CB = keep ? cn1 : CB;  HB = keep ? hn1 : HB;                           \
      }

      if (fat) {
        f32x4 acc1 = {0.f, 0.f, 0.f, 0.f};
        acc1 = __builtin_amdgcn_mfma_f32_16x16x32_bf16(Af10, Bf0, acc1, 0, 0, 0);
        acc1 = __builtin_amdgcn_mfma_f32_16x16x32_bf16(Af11, Bf1, acc1, 0, 0, 0);
        CELL2(acc0, acc1, c0, h0, c1, h1)
        *(unsigned*)(hb + PN + hwb32) = f2bf2(h0, h1);
      } else if ((T & 3) == rr) {
        // rotation step: fixed tile + tile 12 (state via LDS)
        f32x4 acc2 = {0.f, 0.f, 0.f, 0.f};
        acc2 = __builtin_amdgcn_mfma_f32_16x16x32_bf16(Af10, Bf0, acc2, 0, 0, 0);
        acc2 = __builtin_amdgcn_mfma_f32_16x16x32_bf16(Af11, Bf1, acc2, 0, 0, 0);
        float cO = 0.f, hO = 0.f;
        if (jj < 2) { cO = cst12[ci]; hO = hst12[ci]; }
        CELL2(acc0, acc2, c0, h0, cO, hO)
        *(short*)(hb + PN + hwb16) = f2bf(h0);
        if (jj < 2) {
          cst12[ci] = cO; hst12[ci] = hO;
          *(short*)(hb + PN + hw12) = f2bf(hO);
        }
      } else {
        // single fused-fraction cell: 5 exp2 + 2 rcp
        float eA = __builtin_amdgcn_exp2f(acc0[0]);
        float eB = __builtin_amdgcn_exp2f(acc0[1]);
        float eC = __builtin_amdgcn_exp2f(acc0[2]);
        float eG = __builtin_amdgcn_exp2f(acc0[3]);
        float a1 = 1.f + eA, bb1 = 1.f + eB, cc1 = 1.f + eC, g1 = 1.f + eG;
        float P   = a1 * cc1;
        float t1  = __builtin_fmaf(-eC, bb1, bb1);
        float num = __builtin_fmaf(c0, P, t1);
        float den = P * bb1;
        float cn  = num * __builtin_amdgcn_rcpf(den);
        float cl  = fminf(cn * -2.885390082f, 40.0f);
        float eH  = __builtin_amdgcn_exp2f(cl);
        float hd  = g1 * (1.f + eH);
        float hn  = (1.f - eH) * __builtin_amdgcn_rcpf(hd);
        c0 = keep ? cn : c0;
        h0 = keep ? hn : h0;
        *(short*)(hb + PN + hwb16) = f2bf(h0);
      }
#undef CELL2
    }
  }

  // ---- final h -> MLP -> sigmoid
  if (fat) {
    hfin[bB * 52 + 2 * p]     = h0;
    hfin[bB * 52 + 2 * p + 1] = h1;
  } else {
    hfin[bB * 52 + jhF] = h0;
  }
  __syncthreads();                       // hst12 final values visible
  if (wv == 0 && jj < 2) hfin[bB * 52 + 48 + jj] = hst12[ci];
  __syncthreads();
  for (int idx = tid; idx < 16 * 64; idx += 512) {
    int b = idx >> 6, m = idx & 63;
    if (m < HID) {
      float s = b1[m];
      for (int j2 = 0; j2 < HID; ++j2) s += hfin[b * 52 + j2] * W1[m * HID + j2];
      mlp_hid[b * 52 + m] = s;
    }
  }
  __syncthreads();
  if (tid < 16) {
    float s = b2[0];
    for (int m2 = 0; m2 < HID; ++m2) s += mlp_hid[tid * 52 + m2] * W2[m2];
    out[b0 + tid] = fsigm(s);
  }
}

extern "C" void kernel_launch(void* const* d_in, const int* in_sizes, int n_in,
                              void* d_out, int out_size, void* d_ws, size_t ws_size,
                              hipStream_t stream) {
  const int*   tokens = (const int*)  d_in[0];
  const float* emb    = (const float*)d_in[1];
  const float* W_ih   = (const float*)d_in[2];
  const float* W_hh   = (const float*)d_in[3];
  const float* b_ih   = (const float*)d_in[4];
  const float* b_hh   = (const float*)d_in[5];
  const float* W1     = (const float*)d_in[6];
  const float* b1     = (const float*)d_in[7];
  const float* W2     = (const float*)d_in[8];
  const float* b2     = (const float*)d_in[9];
  float* outp  = (float*)d_out;
  short* Apack = (short*)d_ws;                 // 13312 bf16 = 26.6 KB

  hipLaunchKernelGGL(prep_kernel, dim3(52), dim3(256), 0, stream,
                     emb, W_ih, W_hh, b_ih, b_hh, Apack);
  hipLaunchKernelGGL(lstm_kernel, dim3(BATCH / 16), dim3(512), 0, stream,
                     tokens, Apack, W1, b1, W2, b2, outp);
}

// Round 11
// 811.468 us; speedup vs baseline: 1.1205x; 1.1205x over previous
//
#include <hip/hip_runtime.h>

#define BATCH 4096
#define SEQ   2048
#define EMB   10
#define HID   50
#define VOCAB 14
#define TROW  2052     // token row stride bytes (u8): /4=513 ≡ 1 mod 32 -> conflict-free

using bf16x8 = __attribute__((ext_vector_type(8))) short;
using f32x4  = __attribute__((ext_vector_type(4))) float;

__device__ __forceinline__ short f2bf(float f) {
  unsigned u = __builtin_bit_cast(unsigned, f);
  u = (u + 0x7FFFu + ((u >> 16) & 1u)) >> 16;   // round-to-nearest-even
  return (short)u;
}
__device__ __forceinline__ unsigned f2bf2(float lo, float hi) {
  return (unsigned)(unsigned short)f2bf(lo) | ((unsigned)(unsigned short)f2bf(hi) << 16);
}
__device__ __forceinline__ float fsigm(float x) {
  return __builtin_amdgcn_rcpf(1.0f + __builtin_amdgcn_exp2f(x * -1.44269504f));
}

// ---------------------------------------------------------------------------
// Pack A fragments (bf16, pre-scaled) for mfma_f32_16x16x32_bf16.
// 13 flat tiles. Tile tid, row m: q=m>>2 (dest quad), g=m&3 (gate).
//   tid<10  (fat pairs)  : jh = 2*((tid>>1)*4 + q) + (tid&1)   -> jh 0..39
//   tid>=10 (singles)    : jh = 40 + (tid-10)*4 + q            -> jh 40..51 (50,51 pad)
// Fat lanes thus own ADJACENT jh (2p, 2p+1) -> packed b32 h-write.
// i/f/o rows scaled by -log2e, g rows by -2log2e (fused-fraction epilogue).
//   k < 50 : W_hh[R][k]*scale ; k >= 50 : gxi[v=k-50][R]*scale,  R = g*50+jh
// ---------------------------------------------------------------------------
__global__ void prep_kernel(const float* __restrict__ emb,  const float* __restrict__ W_ih,
                            const float* __restrict__ W_hh, const float* __restrict__ b_ih,
                            const float* __restrict__ b_hh, short* __restrict__ Apack) {
  int idx = blockIdx.x * 256 + threadIdx.x;       // total 13*2*64*8 = 13312
  if (idx >= 13 * 2 * 64 * 8) return;
  int j    = idx & 7;
  int lane = (idx >> 3) & 63;
  int kf   = (idx >> 9) & 1;
  int tid  = idx >> 10;                            // tile 0..12
  int m    = lane & 15;
  int q    = m >> 2, g = m & 3;
  int jh   = (tid < 10) ? (2 * ((tid >> 1) * 4 + q) + (tid & 1))
                        : (40 + (tid - 10) * 4 + q);
  int k    = kf * 32 + (lane >> 4) * 8 + j;
  float v = 0.0f;
  if (jh < HID) {
    int R = g * HID + jh;
    float scale = (g == 2) ? -2.885390082f : -1.442695041f;
    if (k < HID) {
      v = W_hh[R * HID + k] * scale;
    } else {
      int vo = k - HID;                            // vocab id 0..13
      float s = b_ih[R] + b_hh[R];
      for (int e = 0; e < EMB; ++e) s += emb[vo * EMB + e] * W_ih[R * EMB + e];
      v = s * scale;
    }
  }
  Apack[idx] = f2bf(v);
}

// ---------------------------------------------------------------------------
// Main: 256 wgs x 512 threads (8 waves), one wg owns 16 batch rows.
// Tiles per wave = {2,2,2,1,1,2,1,2} -> tiles/SIMD = {3,4,3,3} under
// round-robin wave->SIMD AND {4,3,3,3} under block mapping (13 = 3*4+1 is the
// min-max). One-hot duty on single-tile waves 3,4 (never on the 4-tile SIMD).
// Fat waves: B-frag read once, 2 MFMA pairs, paired-rcp fused-fraction cells
// (10 exp2 + 2 rcp), one packed b32 h-write. All LDS addresses loop-invariant;
// tokens staged once to LDS as u8 (no vmem in the loop).
// Best-known configuration (R8, 816 us). R9 (indep accumulators) and R10
// (rotating 13th tile, LDS state) both regressed: per-step time is the MAX
// over waves of the post-barrier serial chain; both variants lengthened it.
// ---------------------------------------------------------------------------
__global__ __launch_bounds__(512, 1) void lstm_kernel(
    const int* __restrict__ tokens, const short* __restrict__ Apack,
    const float* __restrict__ W1, const float* __restrict__ b1,
    const float* __restrict__ W2, const float* __restrict__ b2,
    float* __restrict__ out) {
  __shared__ __align__(16) unsigned char toku8[16 * TROW];   // 32832 B
  __shared__ __align__(16) short hbuf[2][16 * 64];           // 4096 B, swizzled
  __shared__ float hfin[16 * 52];
  __shared__ float mlp_hid[16 * 52];

  const int tid  = threadIdx.x;
  const int lane = tid & 63;
  const int wv   = tid >> 6;
  const int b0   = blockIdx.x * 16;
  const int bB   = lane & 15;          // batch col (B-frag & C col)
  const int jj   = lane >> 4;          // quad

  // wave roles: fat mask {0,1,2,5,7} = 0xA7, singles {3,4,6} = 0x58
  const bool two = (0xA7 >> wv) & 1;
  const int  fr  = __builtin_popcount(0xA7 & ((1 << wv) - 1));  // fat rank
  const int  sr  = __builtin_popcount(0x58 & ((1 << wv) - 1));  // single rank
  const int  p   = fr * 4 + jj;                  // fat: jh pair (2p, 2p+1)
  const int  jhS = 40 + sr * 4 + jj;             // single: jh (50,51 = pad)
  const bool sval = !two && (jhS < HID);

  // persistent A fragments
  const int t0 = two ? (fr * 2) : (10 + sr);
  bf16x8 Af00 = *(const bf16x8*)(Apack + ((t0 * 2 + 0) * 64 + lane) * 8);
  bf16x8 Af01 = *(const bf16x8*)(Apack + ((t0 * 2 + 1) * 64 + lane) * 8);
  bf16x8 Af10 = {}, Af11 = {};
  if (two) {
    Af10 = *(const bf16x8*)(Apack + (((t0 + 1) * 2 + 0) * 64 + lane) * 8);
    Af11 = *(const bf16x8*)(Apack + (((t0 + 1) * 2 + 1) * 64 + lane) * 8);
  }

  // one-hot duty: waves 3,4 -> 56 lanes each (8 batch rows x 7 words)
  const bool ohact = (wv == 3 || wv == 4) && (lane < 56);
  const int ohr   = (wv - 3) * 8 + lane / 7;    // batch row 0..15
  const int ohsub = lane % 7;                    // word covering vocab 2w,2w+1
  const int ohoct = (ohsub < 3) ? 6 : 7;
  const int ohinn = (ohsub < 3) ? (4 + 4 * ohsub) : (4 * (ohsub - 3));
  const int ohb   = ohr * 128 + 16 * ((ohoct + ohr) & 7) + ohinn;
  const int ohv0  = 2 * ohsub, ohv1 = 2 * ohsub + 1;

  // ---- stage tokens (int32 -> u8) and zero hbuf[0]
  for (int i = tid; i < 16 * 512; i += 512) {          // 8192 int4-groups
    int row = i >> 9, c4 = i & 511;
    int4 tv = *(const int4*)&tokens[(b0 + row) * SEQ + 4 * c4];
    unsigned pk = (tv.x & 0xFF) | ((tv.y & 0xFF) << 8) |
                  ((tv.z & 0xFF) << 16) | ((tv.w & 0xFF) << 24);
    *(unsigned*)&toku8[row * TROW + 4 * c4] = pk;
  }
  for (int i = tid; i < 1024; i += 512) hbuf[0][i] = 0;
  __syncthreads();

  // loop-invariant LDS byte offsets (XOR-swizzled 128 B rows)
  char* hb = (char*)hbuf;
  const int rb0   = bB * 128 + 16 * ((jj + bB) & 7);          // B octet jj
  const int rb1   = bB * 128 + 16 * (((jj + 4) + bB) & 7);    // B octet jj+4
  const int hwb32 = bB * 128 + 16 * (((p >> 2) + bB) & 7) + ((4 * p) & 15);
  const int hwb16 = bB * 128 + 16 * (((jhS >> 3) + bB) & 7) + 2 * (jhS & 7);
  const unsigned char* myrow = &toku8[bB * TROW];    // keep-mask tokens
  const unsigned char* ohtok = &toku8[ohr * TROW];   // one-hot tokens

  // one-hot for t=0
  if (ohact) {
    int tk = ohtok[0];
    unsigned wb = ((tk == ohv0) ? 0x3F80u : 0u) | ((tk == ohv1) ? 0x3F800000u : 0u);
    *(unsigned*)(hb + ohb) = wb;
  }

  float c0 = 0.f, h0 = 0.f, c1 = 0.f, h1 = 0.f;
  unsigned mp = 0;

  for (int t = 0; t < SEQ; t += 16) {
#pragma unroll
    for (int u = 0; u < 16; ++u) {
      const int T  = t + u;
      const int PB = (u & 1) * 2048, PN = PB ^ 2048;
      __syncthreads();   // hbuf[PB] ready; LDS-only -> lgkmcnt drain

      bf16x8 Bf0 = *(const bf16x8*)(hb + PB + rb0);
      bf16x8 Bf1 = *(const bf16x8*)(hb + PB + rb1);
      if ((u & 3) == 0) mp = *(const unsigned*)(myrow + T);   // tokens T..T+3

      f32x4 acc0 = {0.f, 0.f, 0.f, 0.f};
      acc0 = __builtin_amdgcn_mfma_f32_16x16x32_bf16(Af00, Bf0, acc0, 0, 0, 0);
      acc0 = __builtin_amdgcn_mfma_f32_16x16x32_bf16(Af01, Bf1, acc0, 0, 0, 0);
      f32x4 acc1 = {0.f, 0.f, 0.f, 0.f};
      if (two) {
        acc1 = __builtin_amdgcn_mfma_f32_16x16x32_bf16(Af10, Bf0, acc1, 0, 0, 0);
        acc1 = __builtin_amdgcn_mfma_f32_16x16x32_bf16(Af11, Bf1, acc1, 0, 0, 0);
      }

      // one-hot for step T+1 into hbuf[PN] (waves 3,4; token-only dependency)
      if (ohact && T + 1 < SEQ) {
        int tk = ohtok[T + 1];
        unsigned wb = ((tk == ohv0) ? 0x3F80u : 0u) |
                      ((tk == ohv1) ? 0x3F800000u : 0u);
        *(unsigned*)(hb + PN + ohb) = wb;
      }

      const bool keep = (((mp >> (8 * (u & 3))) & 0xFF) != 0);

      if (two) {
        // paired fused-fraction cells: 10 exp2 + 2 rcp
        float eA0 = __builtin_amdgcn_exp2f(acc0[0]);
        float eB0 = __builtin_amdgcn_exp2f(acc0[1]);
        float eC0 = __builtin_amdgcn_exp2f(acc0[2]);
        float eG0 = __builtin_amdgcn_exp2f(acc0[3]);
        float eA1 = __builtin_amdgcn_exp2f(acc1[0]);
        float eB1 = __builtin_amdgcn_exp2f(acc1[1]);
        float eC1 = __builtin_amdgcn_exp2f(acc1[2]);
        float eG1 = __builtin_amdgcn_exp2f(acc1[3]);
        float a10 = 1.f + eA0, b10 = 1.f + eB0, c10 = 1.f + eC0, g10 = 1.f + eG0;
        float a11 = 1.f + eA1, b11 = 1.f + eB1, c11 = 1.f + eC1, g11 = 1.f + eG1;
        float P0 = a10 * c10, P1 = a11 * c11;
        float t10 = __builtin_fmaf(-eC0, b10, b10);
        float t11 = __builtin_fmaf(-eC1, b11, b11);
        float num0 = __builtin_fmaf(c0, P0, t10);
        float num1 = __builtin_fmaf(c1, P1, t11);
        float den0 = P0 * b10, den1 = P1 * b11;
        float r  = __builtin_amdgcn_rcpf(den0 * den1);
        float cn0 = num0 * (den1 * r);
        float cn1 = num1 * (den0 * r);
        float cl0 = fminf(cn0 * -2.885390082f, 40.0f);
        float cl1 = fminf(cn1 * -2.885390082f, 40.0f);
        float H0 = __builtin_amdgcn_exp2f(cl0);
        float H1 = __builtin_amdgcn_exp2f(cl1);
        float hd0 = g10 * (1.f + H0);
        float hd1 = g11 * (1.f + H1);
        float rh = __builtin_amdgcn_rcpf(hd0 * hd1);
        float hn0 = (1.f - H0) * (hd1 * rh);
        float hn1 = (1.f - H1) * (hd0 * rh);
        c0 = keep ? cn0 : c0;  h0 = keep ? hn0 : h0;
        c1 = keep ? cn1 : c1;  h1 = keep ? hn1 : h1;
        *(unsigned*)(hb + PN + hwb32) = f2bf2(h0, h1);
      } else {
        // single fused-fraction cell: 5 exp2 + 2 rcp
        float eA = __builtin_amdgcn_exp2f(acc0[0]);
        float eB = __builtin_amdgcn_exp2f(acc0[1]);
        float eC = __builtin_amdgcn_exp2f(acc0[2]);
        float eG = __builtin_amdgcn_exp2f(acc0[3]);
        float a1 = 1.f + eA, bb1 = 1.f + eB, cc1 = 1.f + eC, g1 = 1.f + eG;
        float P   = a1 * cc1;
        float t1  = __builtin_fmaf(-eC, bb1, bb1);
        float num = __builtin_fmaf(c0, P, t1);
        float den = P * bb1;
        float cn  = num * __builtin_amdgcn_rcpf(den);
        float cl  = fminf(cn * -2.885390082f, 40.0f);
        float eH  = __builtin_amdgcn_exp2f(cl);
        float hd  = g1 * (1.f + eH);
        float hn  = (1.f - eH) * __builtin_amdgcn_rcpf(hd);
        c0 = keep ? cn : c0;
        h0 = keep ? hn : h0;
        if (sval) *(short*)(hb + PN + hwb16) = f2bf(h0);
      }
    }
  }

  // ---- final h -> MLP -> sigmoid
  if (two) {
    hfin[bB * 52 + 2 * p]     = h0;
    hfin[bB * 52 + 2 * p + 1] = h1;
  } else if (sval) {
    hfin[bB * 52 + jhS] = h0;
  }
  __syncthreads();
  for (int idx = tid; idx < 16 * 64; idx += 512) {
    int b = idx >> 6, m = idx & 63;
    if (m < HID) {
      float s = b1[m];
      for (int j2 = 0; j2 < HID; ++j2) s += hfin[b * 52 + j2] * W1[m * HID + j2];
      mlp_hid[b * 52 + m] = s;
    }
  }
  __syncthreads();
  if (tid < 16) {
    float s = b2[0];
    for (int m2 = 0; m2 < HID; ++m2) s += mlp_hid[tid * 52 + m2] * W2[m2];
    out[b0 + tid] = fsigm(s);
  }
}

extern "C" void kernel_launch(void* const* d_in, const int* in_sizes, int n_in,
                              void* d_out, int out_size, void* d_ws, size_t ws_size,
                              hipStream_t stream) {
  const int*   tokens = (const int*)  d_in[0];
  const float* emb    = (const float*)d_in[1];
  const float* W_ih   = (const float*)d_in[2];
  const float* W_hh   = (const float*)d_in[3];
  const float* b_ih   = (const float*)d_in[4];
  const float* b_hh   = (const float*)d_in[5];
  const float* W1     = (const float*)d_in[6];
  const float* b1     = (const float*)d_in[7];
  const float* W2     = (const float*)d_in[8];
  const float* b2     = (const float*)d_in[9];
  float* outp  = (float*)d_out;
  short* Apack = (short*)d_ws;                 // 13312 bf16 = 26.6 KB

  hipLaunchKernelGGL(prep_kernel, dim3(52), dim3(256), 0, stream,
                     emb, W_ih, W_hh, b_ih, b_hh, Apack);
  hipLaunchKernelGGL(lstm_kernel, dim3(BATCH / 16), dim3(512), 0, stream,
                     tokens, Apack, W1, b1, W2, b2, outp);
}